// Round 7
// baseline (397.089 us; speedup 1.0000x reference)
//
#include <hip/hip_runtime.h>
#include <cstdint>
#include <cstddef>

#define GK0 0.7978845608028654f
#define GC1 0.044715f

typedef __attribute__((ext_vector_type(8))) short short8;
typedef __attribute__((ext_vector_type(4))) float floatx4;

__device__ __forceinline__ unsigned short f2bf(float f) {
  union { float f; unsigned int u; } v; v.f = f;
  unsigned int r = v.u + 0x7fffu + ((v.u >> 16) & 1u);   // RNE
  return (unsigned short)(r >> 16);
}

// async 16B global->LDS; LDS dest = wave-uniform base + lane*16
__device__ __forceinline__ void gl_lds16(const unsigned short* g, unsigned short* l) {
  __builtin_amdgcn_global_load_lds(
      (const __attribute__((address_space(1))) unsigned int*)g,
      (__attribute__((address_space(3))) unsigned int*)l, 16, 0, 0);
}

// ---- prep: NCHW fp32 -> NHWC bf16 transpose (blocks 0..2047, LDS-free)
//            + weight repack [co][ci][3][3] -> wt[khw][co][ci] (blocks 2048..2335)
__global__ __launch_bounds__(256) void k_prep(
    const float* __restrict__ x, const float* __restrict__ w,
    unsigned short* __restrict__ xb, unsigned short* __restrict__ wt,
    float* __restrict__ out) {
  const int bx = blockIdx.x;
  if (bx < 2048) {
    const int b = bx >> 6, h = ((bx & 63) << 1) + (threadIdx.x >> 7);
    const int wcol = threadIdx.x & 127;                  // lane->w: reads coalesced
    const float* src = x + (size_t)b * 64 * 16384 + (size_t)h * 128 + wcol;
    unsigned short* dst = xb + (((size_t)b * 128 + h) * 128 + wcol) * 64;
#pragma unroll
    for (int ch = 0; ch < 8; ch++) {                     // 8 ci per round, ~12 live regs
      float f[8];
#pragma unroll
      for (int j = 0; j < 8; j++) f[j] = src[(size_t)(8 * ch + j) * 16384];
      short8 v;
#pragma unroll
      for (int j = 0; j < 8; j++) v[j] = (short)f2bf(f[j]);
      *(short8*)(dst + ch * 8) = v;
    }
  } else {
    if (bx == 2048) {
      for (int i = threadIdx.x; i < 32 * 128; i += 256) out[i] = 0.0f;
    }
    const int t = (bx - 2048) * 256 + threadIdx.x;
    if (t < 128 * 64 * 9) {
      int co = t / 576; int r = t - co * 576; int ci = r / 9; int khw = r - ci * 9;
      wt[(khw * 128 + co) * 64 + ci] = f2bf(w[t]);
    }
  }
}

// ---- conv + bias + gelu + pool: m97-shape K-loop, dbuf, XOR-swizzled LDS ----
// grid (2 w-halves, 63 h-pairs, 32 b), block 256 (4 waves).
// Tile M=128co x N=128pos (2 h-rows x 64 w), 9 (kh,kw) steps, BK=64ci.
// LDS chunk swizzle: logical (row, ch) stored at row*128B + (ch^(row&7))*16B.
// Staged via gl_lds by permuting which lane fetches which global chunk.
__global__ __launch_bounds__(256, 2) void k_conv(
    const unsigned short* __restrict__ xb, const unsigned short* __restrict__ wt,
    const float* __restrict__ bias, float* __restrict__ out) {
  __shared__ __align__(16) unsigned short xs[2][16384];  // [buf][As 16KB | Bs 16KB]
  const int tid = threadIdx.x, lane = tid & 63, wv = tid >> 6;
  const int w0 = blockIdx.x * 64, h0 = blockIdx.y * 2, b = blockIdx.z;
  const int wm = wv & 1, wn = wv >> 1;                   // co-half, h-row of output
  const int m = lane & 15, q = lane >> 4;

  // staging lane geometry (swizzle): lane l covers phys row base+ (l>>3), chunk l&7
  // -> must FETCH logical chunk (l&7)^(l>>3)
  const int lr = lane >> 3, lco = ((lane & 7) ^ lr) << 3;       // shorts
  const unsigned short* aln = wt + (32 * wv + lr) * 64 + lco;   // +khw*8192 +i*512
  const unsigned short* xbb = xb + (size_t)b * 128 * 8192;
  const int srh = wv >> 1;                                      // staged h-row
  const size_t bln = (size_t)(32 * (wv & 1) + lr) * 64 + lco;

#define STAGE(khw_, bufi_)                                                        \
  {                                                                               \
    const int kh_ = (khw_) / 3, kw_ = (khw_)-3 * kh_;                             \
    unsigned short* Al = &xs[bufi_][0] + wv * 2048;                               \
    const unsigned short* Ag = aln + (khw_)*8192;                                 \
    _Pragma("unroll") for (int i = 0; i < 4; i++) gl_lds16(Ag + i * 512, Al + i * 512); \
    unsigned short* Bl = &xs[bufi_][8192] + wv * 2048;                            \
    const unsigned short* Bg =                                                    \
        xbb + ((size_t)(h0 + srh + kh_) * 128 + w0 + kw_) * 64 + bln;             \
    _Pragma("unroll") for (int i = 0; i < 4; i++) gl_lds16(Bg + i * 512, Bl + i * 512); \
  }

  floatx4 acc[4][4];
#pragma unroll
  for (int i = 0; i < 4; i++)
#pragma unroll
    for (int j = 0; j < 4; j++) acc[i][j] = (floatx4){0.f, 0.f, 0.f, 0.f};

  STAGE(0, 0);

#pragma unroll
  for (int kk = 0; kk < 9; kk++) {
    __syncthreads();               // drains stage(kk) (issued ~1 mfma-phase ago)
    if (kk < 8) STAGE(kk + 1, (kk + 1) & 1);   // into other buf; drained next iter
    const unsigned short* As = &xs[kk & 1][0];
    const unsigned short* Bs = &xs[kk & 1][8192];
#pragma unroll
    for (int half = 0; half < 2; half++) {
      const int coff = (((half << 2) | q) ^ (m & 7)) << 3;   // swizzled chunk
      short8 a[4], bf[4];
#pragma unroll
      for (int mt = 0; mt < 4; mt++)
        a[mt] = *(const short8*)&As[(wm * 64 + mt * 16 + m) * 64 + coff];
#pragma unroll
      for (int nt = 0; nt < 4; nt++)
        bf[nt] = *(const short8*)&Bs[(wn * 64 + nt * 16 + m) * 64 + coff];
#pragma unroll
      for (int mt = 0; mt < 4; mt++)
#pragma unroll
        for (int nt = 0; nt < 4; nt++)
          acc[mt][nt] = __builtin_amdgcn_mfma_f32_16x16x32_bf16(a[mt], bf[nt], acc[mt][nt], 0, 0, 0);
    }
  }

  // epilogue: bias + fast tanh-GELU (y*sigmoid(2u)) + masked pool
  // D layout: col n = wn*64 + nt*16 + m (w' = nt*16+m); row co = wm*64+mt*16+q*4+r
  const float inv_area = 1.0f / (126.0f * 126.0f);
  float* orow = out + b * 128;
#pragma unroll
  for (int mt = 0; mt < 4; mt++)
#pragma unroll
    for (int r2 = 0; r2 < 4; r2++) {
      const int co = wm * 64 + mt * 16 + q * 4 + r2;
      const float bv = bias[co];
      float s = 0.f;
#pragma unroll
      for (int nt = 0; nt < 4; nt++) {
        float y = acc[mt][nt][r2] + bv;
        float u = GK0 * (y + GC1 * y * y * y);
        float e = __expf(-2.0f * u);
        float g = y * __builtin_amdgcn_rcpf(1.0f + e);   // == 0.5y(1+tanh u)
        if (w0 + nt * 16 + m < 126) s += g;              // mask padded w'=126,127
      }
#pragma unroll
      for (int d = 1; d < 16; d <<= 1) s += __shfl_xor(s, d, 64);
      if (m == 0) atomicAdd(&orow[co], s * inv_area);
    }
}

extern "C" void kernel_launch(void* const* d_in, const int* in_sizes, int n_in,
                              void* d_out, int out_size, void* d_ws, size_t ws_size,
                              hipStream_t stream) {
  const float* x    = (const float*)d_in[0];
  const float* w    = (const float*)d_in[1];
  const float* bias = (const float*)d_in[2];
  float* out = (float*)d_out;

  const size_t xb_elems = (size_t)32 * 128 * 8192;       // 64 MiB bf16 NHWC
  unsigned short* xbuf = (unsigned short*)d_ws;
  unsigned short* wbuf = xbuf + xb_elems + 8192;         // 16 KB slack (B halo overreads)
  if (ws_size < xb_elems * 2 + 16384 + (size_t)9 * 128 * 64 * 2) return;

  k_prep<<<2336, 256, 0, stream>>>(x, w, xbuf, wbuf, out);
  k_conv<<<dim3(2, 63, 32), 256, 0, stream>>>(xbuf, wbuf, bias, out);
}